// Round 17
// baseline (256.608 us; speedup 1.0000x reference)
//
#include <hip/hip_runtime.h>

#define NTOK 2048
#define DD   512
#define FFD  2048
#define NE   64
#define KSEL 4
#define NPAIR (NTOK*KSEL)   // 8192
#define BM 192
#define BK 128
#define NT 128              // static tile-slot upper bound
#define HROWS (NPAIR + 256) // slack for padded A-row reads in gemm_out

typedef short s16x8 __attribute__((ext_vector_type(8)));
typedef float f32x4 __attribute__((ext_vector_type(4)));

typedef const __attribute__((address_space(1))) char* gptr_t;
typedef __attribute__((address_space(3))) char* lptr_t;

static __device__ __forceinline__ unsigned short f2bf(float f) {
    unsigned int u = __builtin_bit_cast(unsigned int, f);
    u += 0x7FFFu + ((u >> 16) & 1u);   // RNE
    return (unsigned short)(u >> 16);
}

// pack float4 -> 4 bf16 (8B), swizzled write into a 128B bf16 row (R15 format)
static __device__ __forceinline__ void packwrite8(char* rowbase, int n, int kb, float4 v) {
    unsigned int lo = (unsigned int)f2bf(v.x) | ((unsigned int)f2bf(v.y) << 16);
    unsigned int hi = (unsigned int)f2bf(v.z) | ((unsigned int)f2bf(v.w) << 16);
    *(uint2*)(rowbase + n * 128 + (kb ^ ((n & 7) << 4))) = make_uint2(lo, hi);
}

// ---------------- K1: LayerNorm (bf16 out) + wave-parallel top-4 routing ----------------
__global__ __launch_bounds__(256) void k_ln_route(
    const float* __restrict__ x, const float* __restrict__ hw,
    const float* __restrict__ gamma, const float* __restrict__ beta,
    unsigned short* __restrict__ xn_bf, int* __restrict__ counts,
    int* __restrict__ tok_e, float* __restrict__ tok_w)
{
    const int t = blockIdx.x;
    const int tid = threadIdx.x;
    const float* xr = x + (size_t)t * DD;
    float v0 = xr[tid];
    float v1 = xr[tid + 256];
    float s = v0 + v1, s2 = v0*v0 + v1*v1;
    #pragma unroll
    for (int off = 32; off > 0; off >>= 1) {
        s  += __shfl_down(s, off);
        s2 += __shfl_down(s2, off);
    }
    __shared__ float rsum[4], rsum2[4];
    __shared__ float smu, srs;
    const int wid = tid >> 6, lane = tid & 63;
    if (lane == 0) { rsum[wid] = s; rsum2[wid] = s2; }
    __syncthreads();
    if (tid == 0) {
        float a = 0.f, b = 0.f;
        for (int i = 0; i < 4; ++i) { a += rsum[i]; b += rsum2[i]; }
        float mu  = a * (1.f / DD);
        float var = b * (1.f / DD) - mu * mu;
        smu = mu; srs = rsqrtf(var + 1e-5f);
    }
    __syncthreads();
    const float mu = smu, rstd = srs;
    xn_bf[(size_t)t*DD + tid]       = f2bf((v0 - mu) * rstd * gamma[tid]       + beta[tid]);
    xn_bf[(size_t)t*DD + tid + 256] = f2bf((v1 - mu) * rstd * gamma[tid + 256] + beta[tid + 256]);

    if (tid < 64) {   // wave 0: butterfly argmax x4
        float v = hw[(size_t)t*NE + tid];
        int   sel[KSEL]; float sw[KSEL];
        #pragma unroll
        for (int j = 0; j < KSEL; ++j) {
            float m = v; int mi = tid;
            #pragma unroll
            for (int off = 32; off > 0; off >>= 1) {
                float ov = __shfl_xor(m, off);
                int   oi = __shfl_xor(mi, off);
                if (ov > m || (ov == m && oi < mi)) { m = ov; mi = oi; }
            }
            if (tid == mi) v = -1e30f;
            sel[j] = mi; sw[j] = m;
        }
        if (tid == 0) {
            float ssum = sw[0] + sw[1] + sw[2] + sw[3];
            float inv = 1.f / (ssum + 1e-8f);
            #pragma unroll
            for (int j = 0; j < KSEL; ++j) {
                tok_e[t*KSEL + j] = sel[j];
                tok_w[t*KSEL + j] = sw[j] * inv;
                atomicAdd(&counts[sel[j]], 1);
            }
        }
    }
}

// ---------------- K2: parallel scan + tile worklist ----------------
__global__ void k_scan(const int* __restrict__ counts, int* __restrict__ offs,
                       int* __restrict__ cursor, int* __restrict__ tile_e,
                       int* __restrict__ tile_r, int* __restrict__ ntiles)
{
    __shared__ int sc[NE], stc[NE];
    const int tid = threadIdx.x;  // 64
    sc[tid] = counts[tid];
    __syncthreads();
    int off = 0;
    for (int i = 0; i < tid; ++i) off += sc[i];
    offs[tid] = off; cursor[tid] = off;
    if (tid == NE-1) offs[NE] = off + sc[NE-1];
    int tc = (sc[tid] + BM - 1) / BM;
    stc[tid] = tc;
    __syncthreads();
    int toff = 0;
    for (int i = 0; i < tid; ++i) toff += stc[i];
    for (int j = 0; j < tc; ++j) { tile_e[toff + j] = tid; tile_r[toff + j] = off + j*BM; }
    if (tid == NE-1) *ntiles = toff + tc;
}

// ---------------- K3: scatter pairs into expert-grouped slots ----------------
__global__ __launch_bounds__(256) void k_scatter(
    const int* __restrict__ tok_e, const float* __restrict__ tok_w,
    int* __restrict__ cursor, int* __restrict__ pair_tok,
    float* __restrict__ pair_w, int* __restrict__ inv)
{
    int i = blockIdx.x * 256 + threadIdx.x;
    if (i >= NPAIR) return;
    int t = i >> 2;
    int e = tok_e[i];
    int slot = atomicAdd(&cursor[e], 1);
    pair_tok[slot] = t;
    pair_w[slot] = tok_w[i];
    inv[i] = slot;
}

// ---------------- K4/K5: bf16 MFMA GEMM — BK=128 (2x64 halves), counted-vmcnt ----------
// W row-visits are 512B contiguous per step (DRAM page-friendly). 512 threads:
// staging waves 0-3 -> k-half 0, waves 4-7 -> k-half 1 (R15's proven per-half
// layout verbatim). Compute: wave = rg*2+cg owns rows rg*48..+48, cols cg*32..+32.
// Schedule = R16's verified counted-vmcnt (same per-thread counts: 6 A + 4 W).
// LDS 128KB -> 1 block/CU; counted waits keep W in flight across barriers.
template<int KD, bool IS_IN, int NYG>
__global__ __launch_bounds__(512, 2) void k_moe_gemm(
    const unsigned short* __restrict__ Abf,
    const float* __restrict__ W, const float* __restrict__ bias,
    const int* __restrict__ tile_e, const int* __restrict__ tile_r,
    const int* __restrict__ ntiles, const int* __restrict__ offs,
    const int* __restrict__ pr_tok, const float* __restrict__ pr_w,
    unsigned short* __restrict__ Hout, float* __restrict__ Pout)
{
    constexpr int NK = KD / BK;
    const int ti = ((blockIdx.x >> 3) / NYG) * 8 + (blockIdx.x & 7);
    const int yg = (blockIdx.x >> 3) % NYG;
    if (ti >= *ntiles) return;
    const int e    = tile_e[ti];
    const int row0 = tile_r[ti];
    const int rend = offs[e + 1];
    const int n0   = yg * 64;
    const int NOUT = IS_IN ? FFD : DD;

    __shared__ __align__(16) unsigned short As[2 * 2 * BM * 64];  // 96 KB: [buf][half][192][64]
    __shared__ __align__(16) unsigned short Bs[2 * 2 * 64 * 64];  // 32 KB: [buf][half][64][64]

    const int tid  = threadIdx.x;
    const int lane = tid & 63, wave = tid >> 6;
    const int lr = lane & 15, lk = lane >> 4;
    const int hsel = wave >> 2, wl = wave & 3;   // staging role
    const int rg = wave >> 1, cg = wave & 1;     // compute role

    // A sources: per staging-wave, 6 segs of 1KB (8 rows x 128B) within its k-half.
    // dest linear; source chunk pre-swizzled: chunk c of row r gets logical c^(r&7).
    const char* asrc[6];
    #pragma unroll
    for (int i = 0; i < 6; ++i) {
        int seg  = wl * 6 + i;
        int r    = seg * 8 + (lane >> 3);
        int grow = row0 + r;
        int cgk  = (lane & 7) ^ (r & 7);
        size_t rowbase;
        if (IS_IN) {
            int tok = (grow < rend) ? pr_tok[grow] : pr_tok[row0];
            rowbase = (size_t)tok * (KD * 2);
        } else {
            rowbase = (size_t)grow * (KD * 2);   // HROWS slack covers overshoot
        }
        asrc[i] = (const char*)Abf + rowbase + (size_t)cgk * 16 + (size_t)hsel * 128;
    }

    // W: thread covers row n0+(tid>>3); 4 loads of 16B at q*128 + (tid&7)*16 -> 512B/row/step
    const float* wsrc = W + (size_t)e * NOUT * KD + (size_t)(n0 + (tid >> 3)) * KD + (tid & 7) * 4;
    const int bn = tid >> 3;
    const int bj = (tid & 7) * 8;   // byte offset of this thread's 8B within a 128B bf16 half-row

    f32x4 acc[3][2];
    #pragma unroll
    for (int m = 0; m < 3; ++m) {
        acc[m][0] = (f32x4){0.f, 0.f, 0.f, 0.f};
        acc[m][1] = (f32x4){0.f, 0.f, 0.f, 0.f};
    }

    float4 bset0[4], bset1[4];

#define BWRITE(BUFI, SET)                                                         \
    _Pragma("unroll")                                                             \
    for (int q = 0; q < 4; ++q)                                                   \
        packwrite8((char*)Bs + (BUFI) * 16384 + (q >> 1) * 8192, bn,              \
                   bj + (q & 1) * 64, SET[q]);

    // ---- prologue: A(0) glds; W(0)->set0; W(1)->set1; wait vmcnt(4); write B(0) ----
    #pragma unroll
    for (int i = 0; i < 6; ++i)
        __builtin_amdgcn_global_load_lds((gptr_t)asrc[i],
            (lptr_t)((char*)As + hsel * 24576 + (wl * 6 + i) * 1024), 16, 0, 0);
    __builtin_amdgcn_sched_barrier(0);
    #pragma unroll
    for (int q = 0; q < 4; ++q)
        bset0[q] = *(const float4*)(wsrc + q * 32);
    __builtin_amdgcn_sched_barrier(0);
    #pragma unroll
    for (int q = 0; q < 4; ++q)
        bset1[q] = *(const float4*)(wsrc + q * 32 + BK);
    __builtin_amdgcn_sched_barrier(0);
    asm volatile("s_waitcnt vmcnt(4)" ::: "memory");   // A(0)+W(0) retired; W(1) flying
    __builtin_amdgcn_sched_barrier(0);
    BWRITE(0, bset0);

    int buf = 0;

#define GEMM_STEP(KT, SUSE, SISS)                                                        \
    {                                                                                    \
        if ((KT) == NK - 1) {                                                            \
            asm volatile("s_waitcnt vmcnt(0) lgkmcnt(0)" ::: "memory");                  \
        } else {                                                                         \
            asm volatile("s_waitcnt vmcnt(4) lgkmcnt(0)" ::: "memory");                  \
        }                                                                                \
        __builtin_amdgcn_s_barrier();                                                    \
        __builtin_amdgcn_sched_barrier(0);                                               \
        const int nbuf_ = buf ^ 1;                                                       \
        if ((KT) + 1 < NK) {                                                             \
            _Pragma("unroll")                                                            \
            for (int i = 0; i < 6; ++i)                                                  \
                __builtin_amdgcn_global_load_lds(                                        \
                    (gptr_t)(asrc[i] + (size_t)((KT) + 1) * 256),                        \
                    (lptr_t)((char*)As + nbuf_ * 49152 + hsel * 24576                    \
                             + (wl * 6 + i) * 1024), 16, 0, 0);                          \
        }                                                                                \
        __builtin_amdgcn_sched_barrier(0);                                               \
        if ((KT) + 2 < NK) {                                                             \
            _Pragma("unroll")                                                            \
            for (int q = 0; q < 4; ++q)                                                  \
                SISS[q] = *(const float4*)(wsrc + q * 32 + ((KT) + 2) * BK);             \
        }                                                                                \
        __builtin_amdgcn_sched_barrier(0);                                               \
        {                                                                                \
            _Pragma("unroll")                                                            \
            for (int h2 = 0; h2 < 2; ++h2) {                                             \
                const char* Ab = (const char*)As + buf * 49152 + h2 * 24576;             \
                const char* Bb = (const char*)Bs + buf * 16384 + h2 * 8192;              \
                _Pragma("unroll")                                                        \
                for (int h = 0; h < 2; ++h) {                                            \
                    const int koff = h * 64 + lk * 16;                                   \
                    const int swz  = koff ^ ((lr & 7) << 4);                             \
                    s16x8 af[3], bfr[2];                                                 \
                    _Pragma("unroll")                                                    \
                    for (int m = 0; m < 3; ++m)                                          \
                        af[m] = *(const s16x8*)(Ab + (rg * 48 + m * 16 + lr) * 128 + swz);\
                    _Pragma("unroll")                                                    \
                    for (int n = 0; n < 2; ++n)                                          \
                        bfr[n] = *(const s16x8*)(Bb + (cg * 32 + n * 16 + lr) * 128 + swz);\
                    _Pragma("unroll")                                                    \
                    for (int m = 0; m < 3; ++m) {                                        \
                        acc[m][0] = __builtin_amdgcn_mfma_f32_16x16x32_bf16(             \
                            af[m], bfr[0], acc[m][0], 0, 0, 0);                          \
                        acc[m][1] = __builtin_amdgcn_mfma_f32_16x16x32_bf16(             \
                            af[m], bfr[1], acc[m][1], 0, 0, 0);                          \
                    }                                                                    \
                }                                                                        \
            }                                                                            \
        }                                                                                \
        __builtin_amdgcn_sched_barrier(0);                                               \
        if ((KT) + 1 < NK) {                                                             \
            if ((KT) + 2 < NK) asm volatile("s_waitcnt vmcnt(10)" ::: "memory");         \
            else               asm volatile("s_waitcnt vmcnt(6)" ::: "memory");          \
            __builtin_amdgcn_sched_barrier(0);                                           \
            BWRITE(nbuf_, SUSE);                                                         \
        }                                                                                \
        buf ^= 1;                                                                        \
    }

    for (int kt = 0; kt < NK; kt += 2) {
        GEMM_STEP(kt,     bset1, bset0);   // consume W(kt+1)=set1, issue W(kt+2)->set0
        GEMM_STEP(kt + 1, bset0, bset1);   // consume W(kt+2)=set0, issue W(kt+3)->set1
    }
#undef GEMM_STEP
#undef BWRITE

    // epilogue: C row = rg*48 + m*16 + lk*4 + r, col = n0 + cg*32 + n*16 + lr
    #pragma unroll
    for (int m = 0; m < 3; ++m) {
        #pragma unroll
        for (int r = 0; r < 4; ++r) {
            int row = row0 + rg * 48 + m * 16 + lk * 4 + r;
            if (row < rend) {
                if (IS_IN) {
                    #pragma unroll
                    for (int n = 0; n < 2; ++n) {
                        int f = n0 + cg * 32 + n * 16 + lr;
                        float v = acc[m][n][r] + bias[e * FFD + f];
                        v = v / (1.f + __expf(-v));
                        Hout[(size_t)row * FFD + f] = f2bf(v);
                    }
                } else {
                    float pw = pr_w[row];
                    #pragma unroll
                    for (int n = 0; n < 2; ++n) {
                        int d = n0 + cg * 32 + n * 16 + lr;
                        Pout[(size_t)row * DD + d] = (acc[m][n][r] + bias[e * DD + d]) * pw;
                    }
                }
            }
        }
    }
}

// ---------------- K6: per-token combine of 4 expert contributions ----------------
__global__ __launch_bounds__(128) void k_combine(
    const float* __restrict__ pout, const int* __restrict__ inv,
    float* __restrict__ out)
{
    const int t = blockIdx.x;
    const int tid = threadIdx.x;   // 128 threads * float4 = 512 floats
    const float4* p0 = (const float4*)(pout + (size_t)inv[t*4+0]*DD);
    const float4* p1 = (const float4*)(pout + (size_t)inv[t*4+1]*DD);
    const float4* p2 = (const float4*)(pout + (size_t)inv[t*4+2]*DD);
    const float4* p3 = (const float4*)(pout + (size_t)inv[t*4+3]*DD);
    float4 a = p0[tid], b = p1[tid], c = p2[tid], d = p3[tid];
    float4 r;
    r.x = a.x + b.x + c.x + d.x;
    r.y = a.y + b.y + c.y + d.y;
    r.z = a.z + b.z + c.z + d.z;
    r.w = a.w + b.w + c.w + d.w;
    ((float4*)(out + (size_t)t*DD))[tid] = r;
}

extern "C" void kernel_launch(void* const* d_in, const int* in_sizes, int n_in,
                              void* d_out, int out_size, void* d_ws, size_t ws_size,
                              hipStream_t stream)
{
    const float* x     = (const float*)d_in[0];
    const float* hw    = (const float*)d_in[1];
    const float* Win   = (const float*)d_in[2];
    const float* bin   = (const float*)d_in[3];
    const float* Wout  = (const float*)d_in[4];
    const float* bout  = (const float*)d_in[5];
    const float* gamma = (const float*)d_in[6];
    const float* beta  = (const float*)d_in[7];
    float* out = (float*)d_out;

    char* ws = (char*)d_ws;
    size_t o = 0;
    unsigned short* xn_bf = (unsigned short*)(ws + o); o += (size_t)NTOK * DD * 2;    // 2 MB
    unsigned short* H     = (unsigned short*)(ws + o); o += (size_t)HROWS * FFD * 2;  // 34.3 MB
    float* pout   = (float*)(ws + o); o += (size_t)NPAIR * DD * 4;                    // 16 MB
    int*   counts = (int*)(ws + o);   o += 256;
    int*   offs   = (int*)(ws + o);   o += 512;
    int*   cursor = (int*)(ws + o);   o += 256;
    int*   tok_e  = (int*)(ws + o);   o += (size_t)NPAIR * 4;
    float* tok_w  = (float*)(ws + o); o += (size_t)NPAIR * 4;
    int*   inv    = (int*)(ws + o);   o += (size_t)NPAIR * 4;
    int*   pr_tok = (int*)(ws + o);   o += (size_t)NPAIR * 4;
    float* pr_w   = (float*)(ws + o); o += (size_t)NPAIR * 4;
    int*   tile_e = (int*)(ws + o);   o += 512;
    int*   tile_r = (int*)(ws + o);   o += 512;
    int*   ntiles = (int*)(ws + o);   o += 256;
    (void)ws_size; (void)in_sizes; (void)n_in; (void)out_size;

    hipMemsetAsync(counts, 0, 256, stream);
    k_ln_route<<<dim3(NTOK), dim3(256), 0, stream>>>(x, hw, gamma, beta, xn_bf, counts, tok_e, tok_w);
    k_scan<<<dim3(1), dim3(64), 0, stream>>>(counts, offs, cursor, tile_e, tile_r, ntiles);
    k_scatter<<<dim3(NPAIR/256), dim3(256), 0, stream>>>(tok_e, tok_w, cursor, pr_tok, pr_w, inv);

    // XCD-pinned dense decode: bid%8 == ti%8 (all column-blocks of a tile share an XCD)
    k_moe_gemm<DD, true, FFD/64><<<dim3(NT * (FFD/64)), dim3(512), 0, stream>>>(
        xn_bf, Win, bin, tile_e, tile_r, ntiles, offs, pr_tok, pr_w, H, nullptr);
    k_moe_gemm<FFD, false, DD/64><<<dim3(NT * (DD/64)), dim3(512), 0, stream>>>(
        H, Wout, bout, tile_e, tile_r, ntiles, offs, pr_tok, pr_w, nullptr, pout);

    k_combine<<<dim3(NTOK), dim3(128), 0, stream>>>(pout, inv, out);
}

// Round 18
// 244.090 us; speedup vs baseline: 1.0513x; 1.0513x over previous
//
#include <hip/hip_runtime.h>

#define NTOK 2048
#define DD   512
#define FFD  2048
#define NE   64
#define KSEL 4
#define NPAIR (NTOK*KSEL)   // 8192
#define BM 192
#define BK 64
#define NT 128              // static tile-slot upper bound
#define HROWS (NPAIR + 256) // slack for padded A-row reads in gemm_out

typedef short s16x8 __attribute__((ext_vector_type(8)));
typedef float f32x4 __attribute__((ext_vector_type(4)));

typedef const __attribute__((address_space(1))) char* gptr_t;
typedef __attribute__((address_space(3))) char* lptr_t;

static __device__ __forceinline__ unsigned short f2bf(float f) {
    unsigned int u = __builtin_bit_cast(unsigned int, f);
    u += 0x7FFFu + ((u >> 16) & 1u);   // RNE
    return (unsigned short)(u >> 16);
}

// pack float4 -> 4 bf16, swizzled ds_write_b64 into a [n][64] bf16 tile (128B rows)
static __device__ __forceinline__ void packwrite(char* base, int nn, int kb, float4 v) {
    unsigned int lo = (unsigned int)f2bf(v.x) | ((unsigned int)f2bf(v.y) << 16);
    unsigned int hi = (unsigned int)f2bf(v.z) | ((unsigned int)f2bf(v.w) << 16);
    *(uint2*)(base + nn * 128 + (kb ^ ((nn & 7) << 4))) = make_uint2(lo, hi);
}

// ---------------- K1: LayerNorm (bf16 out) + wave-parallel top-4 routing ----------------
__global__ __launch_bounds__(256) void k_ln_route(
    const float* __restrict__ x, const float* __restrict__ hw,
    const float* __restrict__ gamma, const float* __restrict__ beta,
    unsigned short* __restrict__ xn_bf, int* __restrict__ counts,
    int* __restrict__ tok_e, float* __restrict__ tok_w)
{
    const int t = blockIdx.x;
    const int tid = threadIdx.x;
    const float* xr = x + (size_t)t * DD;
    float v0 = xr[tid];
    float v1 = xr[tid + 256];
    float s = v0 + v1, s2 = v0*v0 + v1*v1;
    #pragma unroll
    for (int off = 32; off > 0; off >>= 1) {
        s  += __shfl_down(s, off);
        s2 += __shfl_down(s2, off);
    }
    __shared__ float rsum[4], rsum2[4];
    __shared__ float smu, srs;
    const int wid = tid >> 6, lane = tid & 63;
    if (lane == 0) { rsum[wid] = s; rsum2[wid] = s2; }
    __syncthreads();
    if (tid == 0) {
        float a = 0.f, b = 0.f;
        for (int i = 0; i < 4; ++i) { a += rsum[i]; b += rsum2[i]; }
        float mu  = a * (1.f / DD);
        float var = b * (1.f / DD) - mu * mu;
        smu = mu; srs = rsqrtf(var + 1e-5f);
    }
    __syncthreads();
    const float mu = smu, rstd = srs;
    xn_bf[(size_t)t*DD + tid]       = f2bf((v0 - mu) * rstd * gamma[tid]       + beta[tid]);
    xn_bf[(size_t)t*DD + tid + 256] = f2bf((v1 - mu) * rstd * gamma[tid + 256] + beta[tid + 256]);

    if (tid < 64) {   // wave 0: butterfly argmax x4
        float v = hw[(size_t)t*NE + tid];
        int   sel[KSEL]; float sw[KSEL];
        #pragma unroll
        for (int j = 0; j < KSEL; ++j) {
            float m = v; int mi = tid;
            #pragma unroll
            for (int off = 32; off > 0; off >>= 1) {
                float ov = __shfl_xor(m, off);
                int   oi = __shfl_xor(mi, off);
                if (ov > m || (ov == m && oi < mi)) { m = ov; mi = oi; }
            }
            if (tid == mi) v = -1e30f;
            sel[j] = mi; sw[j] = m;
        }
        if (tid == 0) {
            float ssum = sw[0] + sw[1] + sw[2] + sw[3];
            float inv = 1.f / (ssum + 1e-8f);
            #pragma unroll
            for (int j = 0; j < KSEL; ++j) {
                tok_e[t*KSEL + j] = sel[j];
                tok_w[t*KSEL + j] = sw[j] * inv;
                atomicAdd(&counts[sel[j]], 1);
            }
        }
    }
}

// ---------------- K2: parallel scan + tile worklist ----------------
__global__ void k_scan(const int* __restrict__ counts, int* __restrict__ offs,
                       int* __restrict__ cursor, int* __restrict__ tile_e,
                       int* __restrict__ tile_r, int* __restrict__ ntiles)
{
    __shared__ int sc[NE], stc[NE];
    const int tid = threadIdx.x;  // 64
    sc[tid] = counts[tid];
    __syncthreads();
    int off = 0;
    for (int i = 0; i < tid; ++i) off += sc[i];
    offs[tid] = off; cursor[tid] = off;
    if (tid == NE-1) offs[NE] = off + sc[NE-1];
    int tc = (sc[tid] + BM - 1) / BM;
    stc[tid] = tc;
    __syncthreads();
    int toff = 0;
    for (int i = 0; i < tid; ++i) toff += stc[i];
    for (int j = 0; j < tc; ++j) { tile_e[toff + j] = tid; tile_r[toff + j] = off + j*BM; }
    if (tid == NE-1) *ntiles = toff + tc;
}

// ---------------- K3: scatter pairs into expert-grouped slots ----------------
__global__ __launch_bounds__(256) void k_scatter(
    const int* __restrict__ tok_e, const float* __restrict__ tok_w,
    int* __restrict__ cursor, int* __restrict__ pair_tok,
    float* __restrict__ pair_w, int* __restrict__ inv)
{
    int i = blockIdx.x * 256 + threadIdx.x;
    if (i >= NPAIR) return;
    int t = i >> 2;
    int e = tok_e[i];
    int slot = atomicAdd(&cursor[e], 1);
    pair_tok[slot] = t;
    pair_w[slot] = tok_w[i];
    inv[i] = slot;
}

// ---------------- K4/K5: bf16 MFMA GEMM — R15 champion, BNX-driven wave grid --------
// XCD-pinned dense decode: bid%8 == ti%8 (all column-blocks of a tile share an XCD).
// BNX=128: 4 waves in 2x2 grid (96 rows x 64 cols each, MT=6). Both GEMMs now use
// this proven config; gemm_out NYG drops 8->4, halving per-XCD H re-reads and
// making its grid exactly 512 = 2 blocks/CU.
template<int KD, bool IS_IN, int BNX, int NYG>
__global__ __launch_bounds__(256, 2) void k_moe_gemm(
    const unsigned short* __restrict__ Abf,
    const float* __restrict__ W, const float* __restrict__ bias,
    const int* __restrict__ tile_e, const int* __restrict__ tile_r,
    const int* __restrict__ ntiles, const int* __restrict__ offs,
    const int* __restrict__ pr_tok, const float* __restrict__ pr_w,
    unsigned short* __restrict__ Hout, float* __restrict__ Pout)
{
    constexpr int NK = KD / BK;
    constexpr int NB = BNX / 16;        // B float4 loads / thread / k-tile
    constexpr int MT = (BNX == 128) ? 6 : 3;
    const int ti = ((blockIdx.x >> 3) / NYG) * 8 + (blockIdx.x & 7);
    const int yg = (blockIdx.x >> 3) % NYG;
    if (ti >= *ntiles) return;
    const int e    = tile_e[ti];
    const int row0 = tile_r[ti];
    const int rend = offs[e + 1];
    const int n0   = yg * BNX;
    const int NOUT = IS_IN ? FFD : DD;
    const float* __restrict__ Wb = W + (size_t)e * NOUT * KD;

    __shared__ __align__(16) unsigned short As[2 * BM * BK];   // 48 KB
    __shared__ __align__(16) unsigned short Bs[2 * BNX * BK];  // 32/16 KB

    const int tid  = threadIdx.x;
    const int lane = tid & 63, wave = tid >> 6;
    const int wmbase = (BNX == 128) ? (wave >> 1) * 96 : wave * 48;
    const int wnbase = (BNX == 128) ? (wave & 1) * 64 : 0;

    // A-source per-lane pointers: 6 LDS segments of 1KB per wave (8 rows each).
    // dest (row r, chunk c=lane&7) receives logical chunk c^(r&7) -> swizzled-on-read.
    const char* asrc[6];
    #pragma unroll
    for (int i = 0; i < 6; ++i) {
        int seg  = wave * 6 + i;
        int r    = seg * 8 + (lane >> 3);
        int grow = row0 + r;
        int cg   = (lane & 7) ^ (r & 7);
        size_t rowbase;
        if (IS_IN) {
            int tok = (grow < rend) ? pr_tok[grow] : pr_tok[row0];
            rowbase = (size_t)tok * (KD * 2);
        } else {
            rowbase = (size_t)grow * (KD * 2);   // HROWS slack covers overshoot
        }
        asrc[i] = (const char*)Abf + rowbase + (size_t)cg * 16;
    }

    const float* wsrc0 = Wb + (size_t)(n0 + (tid >> 4)) * KD + (tid & 15) * 4;
    const int nb = tid >> 4;
    const int kb = (tid & 15) * 8;

    f32x4 acc[MT][4];
    #pragma unroll
    for (int m = 0; m < MT; ++m)
        #pragma unroll
        for (int n = 0; n < 4; ++n)
            acc[m][n] = (f32x4){0.f, 0.f, 0.f, 0.f};

    // ---- prologue: stage k-tile 0 into buffer 0 ----
    {
        #pragma unroll
        for (int i = 0; i < 6; ++i)
            __builtin_amdgcn_global_load_lds((gptr_t)asrc[i],
                (lptr_t)((char*)As + (wave * 6 + i) * 1024), 16, 0, 0);
        float4 breg[NB];
        #pragma unroll
        for (int i = 0; i < NB; ++i)
            breg[i] = *(const float4*)(wsrc0 + (size_t)i * 16 * KD);
        #pragma unroll
        for (int i = 0; i < NB; ++i)
            packwrite((char*)Bs, nb + i * 16, kb, breg[i]);
    }
    __syncthreads();

    int buf = 0;
    for (int kt = 0; kt < NK; ++kt) {
        const int k0n = (kt + 1) * BK;
        float4 bregN[NB];
        if (kt + 1 < NK) {
            // issue next k-tile stage EARLY: A direct-to-LDS, B to regs
            #pragma unroll
            for (int i = 0; i < 6; ++i)
                __builtin_amdgcn_global_load_lds((gptr_t)(asrc[i] + (size_t)k0n * 2),
                    (lptr_t)((char*)As + (buf ^ 1) * (BM * BK * 2) + (wave * 6 + i) * 1024),
                    16, 0, 0);
            #pragma unroll
            for (int i = 0; i < NB; ++i)
                bregN[i] = *(const float4*)(wsrc0 + (size_t)i * 16 * KD + k0n);
        }
        __builtin_amdgcn_sched_barrier(0);   // keep load-issue ahead of compute

        const char* Ab = (const char*)As + buf * (BM * BK * 2);
        const char* Bb = (const char*)Bs + buf * (BNX * BK * 2);
        #pragma unroll
        for (int h = 0; h < 2; ++h) {
            s16x8 af[MT], bfr[4];
            const int koff = h * 64 + (lane >> 4) * 16;
            #pragma unroll
            for (int m = 0; m < MT; ++m) {
                int row = wmbase + m * 16 + (lane & 15);
                af[m] = *(const s16x8*)(Ab + row * 128 + (koff ^ ((row & 7) << 4)));
            }
            #pragma unroll
            for (int n = 0; n < 4; ++n) {
                int row = wnbase + n * 16 + (lane & 15);
                bfr[n] = *(const s16x8*)(Bb + row * 128 + (koff ^ ((row & 7) << 4)));
            }
            #pragma unroll
            for (int m = 0; m < MT; ++m)
                #pragma unroll
                for (int n = 0; n < 4; ++n)
                    acc[m][n] = __builtin_amdgcn_mfma_f32_16x16x32_bf16(af[m], bfr[n], acc[m][n], 0, 0, 0);
        }
        __builtin_amdgcn_sched_barrier(0);   // don't hoist convert's vmcnt-wait above MFMA

        if (kt + 1 < NK) {
            char* Bw = (char*)Bs + (buf ^ 1) * (BNX * BK * 2);
            #pragma unroll
            for (int i = 0; i < NB; ++i)
                packwrite(Bw, nb + i * 16, kb, bregN[i]);
        }
        __syncthreads();   // drains vmcnt(0): A-lds for next buf + B ds_writes
        buf ^= 1;
    }

    // epilogue: C row = (lane>>4)*4 + reg, col = lane&15
    #pragma unroll
    for (int m = 0; m < MT; ++m) {
        #pragma unroll
        for (int r = 0; r < 4; ++r) {
            int row = row0 + wmbase + m * 16 + (lane >> 4) * 4 + r;
            if (row < rend) {
                if (IS_IN) {
                    #pragma unroll
                    for (int n = 0; n < 4; ++n) {
                        int f = n0 + wnbase + n * 16 + (lane & 15);
                        float v = acc[m][n][r] + bias[e * FFD + f];
                        v = v / (1.f + __expf(-v));
                        Hout[(size_t)row * FFD + f] = f2bf(v);
                    }
                } else {
                    float pw = pr_w[row];
                    #pragma unroll
                    for (int n = 0; n < 4; ++n) {
                        int d = n0 + wnbase + n * 16 + (lane & 15);
                        Pout[(size_t)row * DD + d] = (acc[m][n][r] + bias[e * DD + d]) * pw;
                    }
                }
            }
        }
    }
}

// ---------------- K6: per-token combine of 4 expert contributions ----------------
__global__ __launch_bounds__(128) void k_combine(
    const float* __restrict__ pout, const int* __restrict__ inv,
    float* __restrict__ out)
{
    const int t = blockIdx.x;
    const int tid = threadIdx.x;   // 128 threads * float4 = 512 floats
    const float4* p0 = (const float4*)(pout + (size_t)inv[t*4+0]*DD);
    const float4* p1 = (const float4*)(pout + (size_t)inv[t*4+1]*DD);
    const float4* p2 = (const float4*)(pout + (size_t)inv[t*4+2]*DD);
    const float4* p3 = (const float4*)(pout + (size_t)inv[t*4+3]*DD);
    float4 a = p0[tid], b = p1[tid], c = p2[tid], d = p3[tid];
    float4 r;
    r.x = a.x + b.x + c.x + d.x;
    r.y = a.y + b.y + c.y + d.y;
    r.z = a.z + b.z + c.z + d.z;
    r.w = a.w + b.w + c.w + d.w;
    ((float4*)(out + (size_t)t*DD))[tid] = r;
}

extern "C" void kernel_launch(void* const* d_in, const int* in_sizes, int n_in,
                              void* d_out, int out_size, void* d_ws, size_t ws_size,
                              hipStream_t stream)
{
    const float* x     = (const float*)d_in[0];
    const float* hw    = (const float*)d_in[1];
    const float* Win   = (const float*)d_in[2];
    const float* bin   = (const float*)d_in[3];
    const float* Wout  = (const float*)d_in[4];
    const float* bout  = (const float*)d_in[5];
    const float* gamma = (const float*)d_in[6];
    const float* beta  = (const float*)d_in[7];
    float* out = (float*)d_out;

    char* ws = (char*)d_ws;
    size_t o = 0;
    unsigned short* xn_bf = (unsigned short*)(ws + o); o += (size_t)NTOK * DD * 2;    // 2 MB
    unsigned short* H     = (unsigned short*)(ws + o); o += (size_t)HROWS * FFD * 2;  // 34.3 MB
    float* pout   = (float*)(ws + o); o += (size_t)NPAIR * DD * 4;                    // 16 MB
    int*   counts = (int*)(ws + o);   o += 256;
    int*   offs   = (int*)(ws + o);   o += 512;
    int*   cursor = (int*)(ws + o);   o += 256;
    int*   tok_e  = (int*)(ws + o);   o += (size_t)NPAIR * 4;
    float* tok_w  = (float*)(ws + o); o += (size_t)NPAIR * 4;
    int*   inv    = (int*)(ws + o);   o += (size_t)NPAIR * 4;
    int*   pr_tok = (int*)(ws + o);   o += (size_t)NPAIR * 4;
    float* pr_w   = (float*)(ws + o); o += (size_t)NPAIR * 4;
    int*   tile_e = (int*)(ws + o);   o += 512;
    int*   tile_r = (int*)(ws + o);   o += 512;
    int*   ntiles = (int*)(ws + o);   o += 256;
    (void)ws_size; (void)in_sizes; (void)n_in; (void)out_size;

    hipMemsetAsync(counts, 0, 256, stream);
    k_ln_route<<<dim3(NTOK), dim3(256), 0, stream>>>(x, hw, gamma, beta, xn_bf, counts, tok_e, tok_w);
    k_scan<<<dim3(1), dim3(64), 0, stream>>>(counts, offs, cursor, tile_e, tile_r, ntiles);
    k_scatter<<<dim3(NPAIR/256), dim3(256), 0, stream>>>(tok_e, tok_w, cursor, pr_tok, pr_w, inv);

    // XCD-pinned dense decode: bid%8 == ti%8 (all column-blocks of a tile share an XCD)
    k_moe_gemm<DD, true, 128, FFD/128><<<dim3(NT * (FFD/128)), dim3(256), 0, stream>>>(
        xn_bf, Win, bin, tile_e, tile_r, ntiles, offs, pr_tok, pr_w, H, nullptr);
    k_moe_gemm<FFD, false, 128, DD/128><<<dim3(NT * (DD/128)), dim3(256), 0, stream>>>(
        H, Wout, bout, tile_e, tile_r, ntiles, offs, pr_tok, pr_w, nullptr, pout);

    k_combine<<<dim3(NTOK), dim3(128), 0, stream>>>(pout, inv, out);
}